// Round 9
// baseline (98.828 us; speedup 1.0000x reference)
//
#include <hip/hip_runtime.h>

#define HH 32          // LSTM size
#define TT 20          // total steps (14 kernel + 3 down + 3 up)

typedef float v2f __attribute__((ext_vector_type(2)));

#define LOG2E  1.4426950408889634f
#define LN2    0.6931471805599453f

__device__ __forceinline__ float rl(float v, int k) {
    return __int_as_float(__builtin_amdgcn_readlane(__float_as_int(v), k));
}
__device__ __forceinline__ float fsig(float x) {
    return __builtin_amdgcn_rcpf(1.0f + __builtin_amdgcn_exp2f(-x * LOG2E));
}
__device__ __forceinline__ float ftanh(float x) {
    return 1.0f - 2.0f * __builtin_amdgcn_rcpf(1.0f + __builtin_amdgcn_exp2f(x * (2.0f * LOG2E)));
}

// One block, ONE wave. R8 structure (readlane h-broadcast, lane-local gates
// and cell, no in-loop barriers) + ONE change: the 8 candidate G rows for the
// step are PREFETCHED at the top of the body (addresses depend only on step,
// not on data), so the idx->gates edge is a 12-cycle cndmask tree instead of
// a ~150-cycle ds_read sitting on the carried chain. Residents: whh 128 +
// hc 32 VGPRs; Gc[8] is a 32-VGPR transient (~215 total, cap 256).
__global__ __launch_bounds__(64, 1) void controller_kernel(
    const float* __restrict__ w_ih,      // [128,32]
    const float* __restrict__ w_hh,      // [128,32]
    const float* __restrict__ b_ih,      // [128]
    const float* __restrict__ b_hh,      // [128]
    const float* __restrict__ g_emb,     // [1,32]
    const float* __restrict__ emb_kernel,// [8,32]
    const float* __restrict__ emb_down,  // [3,32]
    const float* __restrict__ emb_up,    // [3,32]
    const float* __restrict__ w_kernel,  // [8,32]
    const float* __restrict__ w_down,    // [3,32]
    const float* __restrict__ w_up,      // [3,32]
    const float* __restrict__ noise,     // [20,8]
    float* __restrict__ out)             // [22] = stats[2] ++ samples[20]
{
    const int t   = threadIdx.x;   // 0..63
    const int q   = t & 31;        // gate-set (lanes 32..63 duplicate — harmless)
    const int cls = t & 7;         // logit class this lane owns

    __shared__ __align__(16) float emb_s[15 * 32];    // 0..7 kern, 8..10 down, 11..13 up, 14 g_emb
    __shared__ __align__(16) float Gv[15 * 32 * 4];   // [e][q][4] = W_ih@emb[e]+bias
    __shared__ __align__(16) float gum_s[TT * 8];
    __shared__ __align__(16) float head_s[2 * 8 * 32]; // down/up heads, rows 3..7 zero

    // ---- stage embeddings, gumbel noise, tail heads ----
    for (int i = t; i < 15 * 32; i += 64) {
        const int r = i >> 5, j = i & 31;
        float v;
        if (r < 8)       v = emb_kernel[i];
        else if (r < 11) v = emb_down[i - 8 * 32];
        else if (r < 14) v = emb_up[i - 11 * 32];
        else             v = g_emb[j];
        emb_s[i] = v;
    }
    for (int i = t; i < TT * 8; i += 64) {
        const float u = noise[i];
        gum_s[i] = -logf(-logf(u * (1.0f - 1e-6f) + 1e-7f));   // off critical path
    }
    for (int i = t; i < 2 * 8 * 32; i += 64) {
        const int bi = i >> 8, r = (i >> 5) & 7, j = i & 31;
        head_s[i] = (r < 3) ? (bi ? w_up[r * 32 + j] : w_down[r * 32 + j]) : 0.0f;
    }

    float bias[4];
#pragma unroll
    for (int g = 0; g < 4; ++g) bias[g] = b_ih[q + 32 * g] + b_hh[q + 32 * g];

    // ---- G precompute into LDS; half-waves split the 15 embeddings ----
    {
        v2f wih[64];                                  // transient; dies before whh loads
#pragma unroll
        for (int g = 0; g < 4; ++g) {
            const float4* p = (const float4*)(w_ih + (q + 32 * g) * HH);
#pragma unroll
            for (int k8 = 0; k8 < 8; ++k8) {
                const float4 a = p[k8];
                wih[g * 16 + 2 * k8]     = (v2f){a.x, a.y};
                wih[g * 16 + 2 * k8 + 1] = (v2f){a.z, a.w};
            }
        }
        __syncthreads();   // emb_s ready
        const int e0 = (t < 32) ? 0 : 8;
        const int e1 = (t < 32) ? 8 : 15;
        for (int e = e0; e < e1; ++e) {
            const float4* ep = (const float4*)(emb_s + e * 32);
            v2f g0 = {0.f,0.f}, g1 = {0.f,0.f}, g2 = {0.f,0.f}, g3 = {0.f,0.f};
#pragma unroll
            for (int k8 = 0; k8 < 8; ++k8) {
                const float4 a = ep[k8];
                const v2f x0 = {a.x, a.y}, x1 = {a.z, a.w};
                g0 += wih[2*k8]    * x0;  g0 += wih[2*k8+1]    * x1;
                g1 += wih[16+2*k8] * x0;  g1 += wih[16+2*k8+1] * x1;
                g2 += wih[32+2*k8] * x0;  g2 += wih[32+2*k8+1] * x1;
                g3 += wih[48+2*k8] * x0;  g3 += wih[48+2*k8+1] * x1;
            }
            *(float4*)(Gv + (e * 32 + q) * 4) =
                make_float4(bias[0] + g0.x + g0.y, bias[1] + g1.x + g1.y,
                            bias[2] + g2.x + g2.y, bias[3] + g3.x + g3.y);
        }
    }
    __syncthreads();       // Gv / gum_s / head_s ready; no barriers after this
    __builtin_amdgcn_sched_barrier(0);

    // ---- resident: whh 4 rows as scalars (128 VGPRs), current head (32) ----
    float whh[128];
#pragma unroll
    for (int g = 0; g < 4; ++g) {
        const float4* p = (const float4*)(w_hh + (q + 32 * g) * HH);
#pragma unroll
        for (int k8 = 0; k8 < 8; ++k8) {
            const float4 a = p[k8];
            whh[g*32 + 4*k8 + 0] = a.x; whh[g*32 + 4*k8 + 1] = a.y;
            whh[g*32 + 4*k8 + 2] = a.z; whh[g*32 + 4*k8 + 3] = a.w;
        }
    }
    float hc[32];                                     // current head row (class cls)
#pragma unroll
    for (int k8 = 0; k8 < 8; ++k8) {
        const float4 a = ((const float4*)(w_kernel + cls * 32))[k8];
        hc[4*k8+0] = a.x; hc[4*k8+1] = a.y; hc[4*k8+2] = a.z; hc[4*k8+3] = a.w;
    }

    // ---- pre-loop: h(0) from gates = G[g_emb] (h(-1)=0) ----
    float c_reg, hn;
    {
        const float4 G0 = *(const float4*)(Gv + (14 * 32 + q) * 4);
        const float ig = fsig(G0.x), gv = ftanh(G0.z), og = fsig(G0.w);
        c_reg = ig * gv;               // c(-1)=0: f-gate contributes nothing
        hn    = og * ftanh(c_reg);
    }
    float lp_sum = 0.0f, ent_sum = 0.0f;

    for (int step = 0; step < TT; ++step) {
        // ---- PREFETCH: 8 candidate G rows for THIS step (uniform addresses,
        //      independent of data -> ds_reads complete long before idx) ----
        const int base = (step < 14) ? 0 : ((step < 17) ? 8 : 11);
        const int nm1  = (step < 14) ? 7 : 2;
        float4 Gc[8];
#pragma unroll
        for (int k = 0; k < 8; ++k) {
            const int kk = (k > nm1) ? nm1 : k;        // clamp: rows >= n never selected
            Gc[k] = *(const float4*)(Gv + ((base + kk) * 32 + q) * 4);
        }
        const float4 gA = ((const float4*)(gum_s + step * 8))[0];
        const float4 gB = ((const float4*)(gum_s + step * 8))[1];

        // ---- broadcast h(step) to uniform scalars (readlane: no LDS) ----
        float sh[32];
#pragma unroll
        for (int k = 0; k < 32; ++k) sh[k] = rl(hn, k);

        // ---- logit(step) for class cls: 32 scalar fmac, 4 chains ----
        float l0 = 0.f, l1 = 0.f, l2 = 0.f, l3 = 0.f;
#pragma unroll
        for (int k = 0; k < 32; k += 4) {
            l0 += hc[k]   * sh[k];
            l1 += hc[k+1] * sh[k+1];
            l2 += hc[k+2] * sh[k+2];
            l3 += hc[k+3] * sh[k+3];
        }
        const int n = (step < 14) ? 8 : 3;
        float l = (l0 + l1) + (l2 + l3);
        l = (cls < n) ? l : -1e9f;

        // ---- matvec for step+1: M = W_hh @ h(step), 128 scalar fmac ----
        float Mi = 0.f, Mf = 0.f, Mg = 0.f, Mo = 0.f;
#pragma unroll
        for (int k = 0; k < 32; ++k) {
            Mi += whh[k]      * sh[k];
            Mf += whh[32 + k] * sh[k];
            Mg += whh[64 + k] * sh[k];
            Mo += whh[96 + k] * sh[k];
        }

        // ---- sampling: 8 readlanes -> uniform stats/argmax (in matvec shadow) ----
        float lv[8];
#pragma unroll
        for (int k = 0; k < 8; ++k) lv[k] = rl(l, k);

        const float v0 = lv[0]+gA.x, v1 = lv[1]+gA.y, v2 = lv[2]+gA.z, v3 = lv[3]+gA.w;
        const float v4 = lv[4]+gB.x, v5 = lv[5]+gB.y, v6 = lv[6]+gB.z, v7 = lv[7]+gB.w;
        // strict > keeps FIRST max index (jnp.argmax); masked lanes are -1e9
        const bool ta = v1 > v0;  const float va = ta?v1:v0;  const int ia = ta?1:0;  const float la = ta?lv[1]:lv[0];
        const bool tb = v3 > v2;  const float vb = tb?v3:v2;  const int ib = tb?3:2;  const float lb = tb?lv[3]:lv[2];
        const bool tc = v5 > v4;  const float vc = tc?v5:v4;  const int ic = tc?5:4;  const float lc = tc?lv[5]:lv[4];
        const bool td = v7 > v6;  const float vd = td?v7:v6;  const int id_= td?7:6;  const float ld = td?lv[7]:lv[6];
        const bool tab = vb > va; const float vab = tab?vb:va; const int iab = tab?ib:ia; const float lab = tab?lb:la;
        const bool tcd = vd > vc; const float vcd = tcd?vd:vc; const int icd = tcd?id_:ic; const float lcd = tcd?ld:lc;
        const bool tf  = vcd > vab;
        const int   idx = tf ? icd : iab;
        const float bl  = tf ? lcd : lab;

        // ---- x(step+1): select prefetched G row via cndmask tree (no memory) ----
        const float4 s01 = (idx & 1) ? Gc[1] : Gc[0];
        const float4 s23 = (idx & 1) ? Gc[3] : Gc[2];
        const float4 s45 = (idx & 1) ? Gc[5] : Gc[4];
        const float4 s67 = (idx & 1) ? Gc[7] : Gc[6];
        const float4 sA  = (idx & 2) ? s23 : s01;
        const float4 sB  = (idx & 2) ? s67 : s45;
        const float4 G4  = (idx & 4) ? sB : sA;

        // ---- cell -> h(step+1) (every lane local; no exchanges) ----
        const float gi_ = G4.x + Mi, gf_ = G4.y + Mf, gg_ = G4.z + Mg, go_ = G4.w + Mo;
        const float ig = fsig(gi_), fg = fsig(gf_), gv = ftanh(gg_), og = fsig(go_);
        c_reg = fg * c_reg + ig * gv;
        hn    = og * ftanh(c_reg);

        // ---- off-chain tail: stats accumulation + stores + head swap ----
        float S = 0.0f, Tm = 0.0f;
#pragma unroll
        for (int k = 0; k < 8; ++k) {
            const float e = __builtin_amdgcn_exp2f(lv[k] * LOG2E);  // masked -> 0
            S += e; Tm += e * lv[k];
        }
        const float lse = __builtin_amdgcn_logf(S) * LN2;
        lp_sum  += bl - lse;
        ent_sum += lse - Tm * __builtin_amdgcn_rcpf(S);
        if (t == 0) out[2 + step] = (float)idx;

        if (step == 13 || step == 16) {              // swap in down/up head for next step
            const float* src = head_s + ((step == 16) ? 8 * 32 : 0) + cls * 32;
#pragma unroll
            for (int k8 = 0; k8 < 8; ++k8) {
                const float4 a = ((const float4*)src)[k8];
                hc[4*k8+0] = a.x; hc[4*k8+1] = a.y; hc[4*k8+2] = a.z; hc[4*k8+3] = a.w;
            }
        }
    }

    if (t == 0) {
        out[0] = lp_sum;
        out[1] = ent_sum;
    }
}

extern "C" void kernel_launch(void* const* d_in, const int* in_sizes, int n_in,
                              void* d_out, int out_size, void* d_ws, size_t ws_size,
                              hipStream_t stream) {
    (void)in_sizes; (void)n_in; (void)out_size; (void)d_ws; (void)ws_size;
    const float* w_ih       = (const float*)d_in[0];
    const float* w_hh       = (const float*)d_in[1];
    const float* b_ih       = (const float*)d_in[2];
    const float* b_hh       = (const float*)d_in[3];
    const float* g_emb      = (const float*)d_in[4];
    const float* emb_kernel = (const float*)d_in[5];
    const float* emb_down   = (const float*)d_in[6];
    const float* emb_up     = (const float*)d_in[7];
    const float* w_kernel   = (const float*)d_in[8];
    const float* w_down     = (const float*)d_in[9];
    const float* w_up       = (const float*)d_in[10];
    const float* noise      = (const float*)d_in[11];
    float* out = (float*)d_out;

    hipLaunchKernelGGL(controller_kernel, dim3(1), dim3(64), 0, stream,
                       w_ih, w_hh, b_ih, b_hh, g_emb, emb_kernel, emb_down,
                       emb_up, w_kernel, w_down, w_up, noise, out);
}

// Round 10
// 93.776 us; speedup vs baseline: 1.0539x; 1.0539x over previous
//
#include <hip/hip_runtime.h>

#define HH 32          // LSTM size
#define TT 20          // total steps (14 kernel + 3 down + 3 up)

typedef float v2f __attribute__((ext_vector_type(2)));

#define LOG2E  1.4426950408889634f
#define LN2    0.6931471805599453f

__device__ __forceinline__ float fsig(float x) {
    return __builtin_amdgcn_rcpf(1.0f + __builtin_amdgcn_exp2f(-x * LOG2E));
}
__device__ __forceinline__ float ftanh(float x) {
    return 1.0f - 2.0f * __builtin_amdgcn_rcpf(1.0f + __builtin_amdgcn_exp2f(x * (2.0f * LOG2E)));
}

// Session-best variant (R7, 94.6 us, absmax 0.0). One block, ONE wave.
// Resident = whh 4 gate rows (128 VGPRs) + hk kernel head (32) -> no spill
// (256-cap lesson from R6). G[e]=W_ih@emb[e]+bias precomputed in LDS; the
// idx->gates edge is one ds_read_b128 overlapped with the next FMA stream.
// i,f,g,o lane-local (no gate shuffles). Sampling: 8 shfl gathers + local
// pairwise strict-> argmax tree. Tail steps (6 of 20) use LDS head partials.
// Next-input table base = CURRENT step (reference scan semantics).
__global__ __launch_bounds__(64, 1) void controller_kernel(
    const float* __restrict__ w_ih,      // [128,32]
    const float* __restrict__ w_hh,      // [128,32]
    const float* __restrict__ b_ih,      // [128]
    const float* __restrict__ b_hh,      // [128]
    const float* __restrict__ g_emb,     // [1,32]
    const float* __restrict__ emb_kernel,// [8,32]
    const float* __restrict__ emb_down,  // [3,32]
    const float* __restrict__ emb_up,    // [3,32]
    const float* __restrict__ w_kernel,  // [8,32]
    const float* __restrict__ w_down,    // [3,32]
    const float* __restrict__ w_up,      // [3,32]
    const float* __restrict__ noise,     // [20,8]
    float* __restrict__ out)             // [22] = stats[2] ++ samples[20]
{
    const int t   = threadIdx.x;   // 0..63
    const int q   = t & 31;        // gate-set (lanes 32..63 duplicate the cell)
    const int cls = t & 7;         // logit class this lane owns

    __shared__ __align__(16) float emb_s[15 * 32];    // 0..7 kern, 8..10 down, 11..13 up, 14 g_emb
    __shared__ __align__(16) float Gv[15 * 32 * 4];   // [e][q][4] = (i,f,g,o) precomp
    __shared__ __align__(16) float h_s[32];
    __shared__ __align__(16) float gum_s[TT * 8];
    __shared__ __align__(16) float head_pre[2 * 64 * 4]; // tail heads (down,up) per-lane float4

    // ---- stage embeddings, gumbel noise, tail-head prearrange ----
    for (int i = t; i < 15 * 32; i += 64) {
        const int r = i >> 5, j = i & 31;
        float v;
        if (r < 8)       v = emb_kernel[i];
        else if (r < 11) v = emb_down[i - 8 * 32];
        else if (r < 14) v = emb_up[i - 11 * 32];
        else             v = g_emb[j];
        emb_s[i] = v;
    }
    for (int i = t; i < TT * 8; i += 64) {
        const float u = noise[i];
        gum_s[i] = -logf(-logf(u * (1.0f - 1e-6f) + 1e-7f));   // off critical path
    }
#pragma unroll
    for (int bi = 0; bi < 2; ++bi) {                 // 0=down, 1=up
        float4 v = make_float4(0.f, 0.f, 0.f, 0.f);
        if (cls < 3) {
            const float* W = (bi == 0) ? w_down : w_up;
            v = *(const float4*)(W + cls * 32 + (t >> 3) * 4);
        }
        *(float4*)(head_pre + (bi * 64 + t) * 4) = v;
    }

    float bias[4];
#pragma unroll
    for (int g = 0; g < 4; ++g) bias[g] = b_ih[q + 32 * g] + b_hh[q + 32 * g];

    // ---- G precompute into LDS; half-waves split the 15 embeddings ----
    {
        v2f wih[64];                                  // transient; dies before whh loads
#pragma unroll
        for (int g = 0; g < 4; ++g) {
            const float4* p = (const float4*)(w_ih + (q + 32 * g) * HH);
#pragma unroll
            for (int k8 = 0; k8 < 8; ++k8) {
                const float4 a = p[k8];
                wih[g * 16 + 2 * k8]     = (v2f){a.x, a.y};
                wih[g * 16 + 2 * k8 + 1] = (v2f){a.z, a.w};
            }
        }
        __syncthreads();   // emb_s ready
        const int e0 = (t < 32) ? 0 : 8;
        const int e1 = (t < 32) ? 8 : 15;
        for (int e = e0; e < e1; ++e) {
            const float4* ep = (const float4*)(emb_s + e * 32);
            v2f g0 = {0.f,0.f}, g1 = {0.f,0.f}, g2 = {0.f,0.f}, g3 = {0.f,0.f};
#pragma unroll
            for (int k8 = 0; k8 < 8; ++k8) {
                const float4 a = ep[k8];
                const v2f x0 = {a.x, a.y}, x1 = {a.z, a.w};
                g0 += wih[2*k8]    * x0;  g0 += wih[2*k8+1]    * x1;
                g1 += wih[16+2*k8] * x0;  g1 += wih[16+2*k8+1] * x1;
                g2 += wih[32+2*k8] * x0;  g2 += wih[32+2*k8+1] * x1;
                g3 += wih[48+2*k8] * x0;  g3 += wih[48+2*k8+1] * x1;
            }
            *(float4*)(Gv + (e * 32 + q) * 4) =
                make_float4(bias[0] + g0.x + g0.y, bias[1] + g1.x + g1.y,
                            bias[2] + g2.x + g2.y, bias[3] + g3.x + g3.y);
        }
    }
    __syncthreads();       // Gv ready
    __builtin_amdgcn_sched_barrier(0);   // keep whh/hk loads out of the G phase

    // ---- resident weights: whh (128 VGPRs) + kernel head hk (32 VGPRs) ----
    v2f whh[64];
#pragma unroll
    for (int g = 0; g < 4; ++g) {
        const float4* p = (const float4*)(w_hh + (q + 32 * g) * HH);
#pragma unroll
        for (int k8 = 0; k8 < 8; ++k8) {
            const float4 a = p[k8];
            whh[g * 16 + 2 * k8]     = (v2f){a.x, a.y};
            whh[g * 16 + 2 * k8 + 1] = (v2f){a.z, a.w};
        }
    }
    v2f hk[16];
#pragma unroll
    for (int k8 = 0; k8 < 8; ++k8) {
        const float4 a = ((const float4*)(w_kernel + cls * 32))[k8];
        hk[2*k8] = (v2f){a.x, a.y}; hk[2*k8+1] = (v2f){a.z, a.w};
    }

    v2f hreg[16];
#pragma unroll
    for (int k = 0; k < 16; ++k) hreg[k] = (v2f){0.f, 0.f};
    float  c_reg = 0.0f;
    float4 G4 = *(const float4*)(Gv + (14 * 32 + q) * 4);   // first x = g_emb
    float  lp_sum = 0.0f, ent_sum = 0.0f;

    for (int step = 0; step < TT; ++step) {
        // ---- A: gates = G4 + W_hh @ h (4 rows lane-local) ----
        v2f ai = {0.f,0.f}, af = {0.f,0.f}, ag = {0.f,0.f}, ao = {0.f,0.f};
#pragma unroll
        for (int k = 0; k < 16; ++k) {
            ai += whh[k]      * hreg[k];
            af += whh[16 + k] * hreg[k];
            ag += whh[32 + k] * hreg[k];
            ao += whh[48 + k] * hreg[k];
        }
        const float gi_ = G4.x + ai.x + ai.y;
        const float gf_ = G4.y + af.x + af.y;
        const float gg_ = G4.z + ag.x + ag.y;
        const float go_ = G4.w + ao.x + ao.y;

        // ---- B: cell (both halves duplicate; lanes 0..31 write h) ----
        const float ig = fsig(gi_), fg = fsig(gf_), gv = ftanh(gg_), og = fsig(go_);
        c_reg = fg * c_reg + ig * gv;
        const float hn = og * ftanh(c_reg);
        if (t < 32) h_s[t] = hn;
        __syncthreads();

        // ---- broadcast h into regs (feeds logit dot and next step's gates) ----
#pragma unroll
        for (int k8 = 0; k8 < 8; ++k8) {
            const float4 hv = ((const float4*)h_s)[k8];
            hreg[2*k8] = (v2f){hv.x, hv.y}; hreg[2*k8+1] = (v2f){hv.z, hv.w};
        }

        // ---- C: logit for class cls ----
        float l;
        if (step < 14) {                       // kernel head: resident, full 32-dot
            v2f s0 = {0.f,0.f}, s1 = {0.f,0.f};
#pragma unroll
            for (int k = 0; k < 16; k += 2) { s0 += hk[k]*hreg[k]; s1 += hk[k+1]*hreg[k+1]; }
            l = (s0.x + s0.y) + (s1.x + s1.y);  // n=8: no masking
        } else {                               // down/up: LDS partial + 3 xor shuffles
            const int bi = (step < 17) ? 0 : 1;
            const float4 hp = *(const float4*)(head_pre + (bi * 64 + t) * 4);
            const float4 hv = ((const float4*)h_s)[t >> 3];
            float p = hp.x*hv.x + hp.y*hv.y + hp.z*hv.z + hp.w*hv.w;
            p += __shfl_xor(p, 8);
            p += __shfl_xor(p, 16);
            p += __shfl_xor(p, 32);
            l = (cls < 3) ? p : -1e9f;
        }

        // ---- D: gather 8 logits; lane-local stats + pairwise argmax tree ----
        float lv[8];
#pragma unroll
        for (int k = 0; k < 8; ++k) lv[k] = __shfl(l, k);

        float S = 0.0f, Tm = 0.0f;
#pragma unroll
        for (int k = 0; k < 8; ++k) {
            const float e = __builtin_amdgcn_exp2f(lv[k] * LOG2E);  // masked -> 0
            S += e; Tm += e * lv[k];
        }
        const float4 gA = ((const float4*)(gum_s + step * 8))[0];
        const float4 gB = ((const float4*)(gum_s + step * 8))[1];
        const float v0 = lv[0]+gA.x, v1 = lv[1]+gA.y, v2 = lv[2]+gA.z, v3 = lv[3]+gA.w;
        const float v4 = lv[4]+gB.x, v5 = lv[5]+gB.y, v6 = lv[6]+gB.z, v7 = lv[7]+gB.w;
        // strict > at every level keeps the FIRST max index (jnp.argmax rule)
        const bool ta = v1 > v0;  const float va = ta?v1:v0;  const int ia = ta?1:0;  const float la = ta?lv[1]:lv[0];
        const bool tb = v3 > v2;  const float vb = tb?v3:v2;  const int ib = tb?3:2;  const float lb = tb?lv[3]:lv[2];
        const bool tc = v5 > v4;  const float vc = tc?v5:v4;  const int ic = tc?5:4;  const float lc = tc?lv[5]:lv[4];
        const bool td = v7 > v6;  const float vd = td?v7:v6;  const int id_= td?7:6;  const float ld = td?lv[7]:lv[6];
        const bool tab = vb > va; const float vab = tab?vb:va; const int iab = tab?ib:ia; const float lab = tab?lb:la;
        const bool tcd = vd > vc; const float vcd = tcd?vd:vc; const int icd = tcd?id_:ic; const float lcd = tcd?ld:lc;
        const bool tf  = vcd > vab;
        const int   idx = tf ? icd : iab;
        const float bl  = tf ? lcd : lab;

        const float lse = __builtin_amdgcn_logf(S) * LN2;
        lp_sum  += bl - lse;
        ent_sum += lse - Tm * __builtin_amdgcn_rcpf(S);
        if (t == 0) out[2 + step] = (float)idx;

        // ---- E: next G4; table base = CURRENT step (reference semantics) ----
        const int base = (step < 14) ? 0 : ((step < 17) ? 8 : 11);
        G4 = *(const float4*)(Gv + ((base + idx) * 32 + q) * 4);
    }

    if (t == 0) {
        out[0] = lp_sum;
        out[1] = ent_sum;
    }
}

extern "C" void kernel_launch(void* const* d_in, const int* in_sizes, int n_in,
                              void* d_out, int out_size, void* d_ws, size_t ws_size,
                              hipStream_t stream) {
    (void)in_sizes; (void)n_in; (void)out_size; (void)d_ws; (void)ws_size;
    const float* w_ih       = (const float*)d_in[0];
    const float* w_hh       = (const float*)d_in[1];
    const float* b_ih       = (const float*)d_in[2];
    const float* b_hh       = (const float*)d_in[3];
    const float* g_emb      = (const float*)d_in[4];
    const float* emb_kernel = (const float*)d_in[5];
    const float* emb_down   = (const float*)d_in[6];
    const float* emb_up     = (const float*)d_in[7];
    const float* w_kernel   = (const float*)d_in[8];
    const float* w_down     = (const float*)d_in[9];
    const float* w_up       = (const float*)d_in[10];
    const float* noise      = (const float*)d_in[11];
    float* out = (float*)d_out;

    hipLaunchKernelGGL(controller_kernel, dim3(1), dim3(64), 0, stream,
                       w_ih, w_hh, b_ih, b_hh, g_emb, emb_kernel, emb_down,
                       emb_up, w_kernel, w_down, w_up, noise, out);
}